// Round 11
// baseline (2814.773 us; speedup 1.0000x reference)
//
#include <hip/hip_runtime.h>

#define B_ 128
#define T_ 256
#define I_ 512
#define H_ 1024

typedef _Float16 f16;
typedef _Float16 v8h __attribute__((ext_vector_type(8)));
typedef _Float16 v2h __attribute__((ext_vector_type(2)));
typedef float v16f __attribute__((ext_vector_type(16)));
typedef int v4i __attribute__((ext_vector_type(4)));

__device__ __forceinline__ float fsigmoid(float x) { return 1.0f / (1.0f + __expf(-x)); }
__device__ __forceinline__ float ftanh(float x) { return 1.0f - 2.0f / (__expf(2.0f * x) + 1.0f); }

__device__ __forceinline__ void gl_lds16(const void* g, void* l) {
    __builtin_amdgcn_global_load_lds(
        (const __attribute__((address_space(1))) unsigned int*)g,
        (__attribute__((address_space(3))) unsigned int*)l, 16, 0, 0);
}
// device-coherent (SC0|SC1): read the coherence point (fresh h)
__device__ __forceinline__ void gl_lds16_coh(const void* g, void* l) {
    __builtin_amdgcn_global_load_lds(
        (const __attribute__((address_space(1))) unsigned int*)g,
        (__attribute__((address_space(3))) unsigned int*)l, 16, 0, 17);
}

// poll 128 packed flags (lanes 0..31 load dwordx4 each); returns when all >= tgt
__device__ __forceinline__ void pollwait(const int* base, int tgt, int lane) {
    if (tgt <= 0) return;
    for (;;) {
        bool ok = true;
        if (lane < 32) {
            v4i v;
            asm volatile("global_load_dwordx4 %0, %1, off sc0 sc1\n\ts_waitcnt vmcnt(0)"
                         : "=&v"(v) : "v"(base + lane * 4) : "memory");
            ok = (v[0] >= tgt) && (v[1] >= tgt) && (v[2] >= tgt) && (v[3] >= tgt);
        }
        if (__ballot(ok) == ~0ULL) return;
        __builtin_amdgcn_s_sleep(1);
    }
}

// ---------------- conversion kernels ----------------
__global__ void k_f32_to_f16(const float* __restrict__ in, f16* __restrict__ out, int n) {
    int i = blockIdx.x * blockDim.x + threadIdx.x;
    int st = gridDim.x * blockDim.x;
    for (; i < n; i += st) out[i] = (f16)in[i];
}
__global__ void k_bias_sum(const float* __restrict__ a, const float* __restrict__ b,
                           float* __restrict__ o, int n) {
    int i = blockIdx.x * blockDim.x + threadIdx.x;
    int st = gridDim.x * blockDim.x;
    for (; i < n; i += st) o[i] = a[i] + b[i];
}

// ---------------- persistent 2-pipeline LSTM, wave-decoupled K-loop ----------------
// 256 WGs x 512 threads, 1 WG/CU. bx = tile*4 + mh*2 + slot.
// slot0 phase p: layer0[t=p]; slot1 phase p: layer1[t=p-1]. h0,h1 both x4 buffers.
// FLAG SEMANTICS: flag value published at end of phase p is p+1, i.e.
//   flag >= k  <=>  phase k-1 COMPLETE. Freshness of data produced in phase q
//   therefore requires flag >= q+1.  (R9/R10 bug: slot1's h1[p-2] is produced in
//   phase p-1 -> needs own >= p; the relaxed own >= p-1 read h1 one step stale.)
// Per-wave gating (LDS cond words set by poller waves):
//   slot0: kw0 pair free (x-only; wave0 slack-polls oth>=p-2 for h0-buffer reuse);
//          kw1-3 on own>=p (wave2 polls, publishes condA)
//   slot1: kw0,1 on oth>=p (wave0 polls -> condA);  kw2,3 on own>=p (wave4 -> condB)
// K-loop: NO WG barriers — per-round pair handshake via monotone LDS counters.
template <int SLOT>
__device__ void run_slot5(int mh, int tile, int widx128,
                          const f16* __restrict__ xh,
                          const f16* __restrict__ wi, const f16* __restrict__ wh,
                          const float* __restrict__ bs,
                          f16* __restrict__ h0, f16* __restrict__ h1,
                          float* __restrict__ out, int* flags, char* lds)
{
    constexpr int K0 = SLOT ? 1024 : 512;   // x/h boundary of combined K
    constexpr int KW = SLOT ? 512 : 384;    // per-kw-window width (K/4)
    constexpr int NR = KW / 64;             // 64-k rounds per window (6 or 8)
    constexpr int NKS = KW / 16;
    const size_t BH = (size_t)B_ * H_;

    const int tid = threadIdx.x;
    const int wave = tid >> 6;
    const int lane = tid & 63;
    const int l31 = lane & 31, khi = lane >> 5;
    const int nw = wave & 1, kw = wave >> 1;
    const int n0 = tile * 16;
    const int rbase = mh * 64;

    // ---- W fragments -> registers (once) ----
    const int gcl = nw * 32 + l31;
    const size_t gr = (size_t)(gcl >> 4) * H_ + n0 + (gcl & 15);
    v8h wfrag[NKS];
#pragma unroll
    for (int s = 0; s < NKS; ++s) {
        const int k = kw * KW + s * 16 + khi * 8;
        const f16* p = (k < K0) ? (wi + gr * K0 + k) : (wh + gr * H_ + (k - K0));
        wfrag[s] = *(const v8h*)p;
    }

    // ---- per-thread cell state + biases (2 cells) ----
    const int urow = tid >> 3;
    const int un = (tid & 7) * 2;
    const float2 bI = *(const float2*)(bs + 0 * H_ + n0 + un);
    const float2 bF = *(const float2*)(bs + 1 * H_ + n0 + un);
    const float2 bG = *(const float2*)(bs + 2 * H_ + n0 + un);
    const float2 bO = *(const float2*)(bs + 3 * H_ + n0 + un);
    float c0r = 0.f, c1r = 0.f;

    int* f_own = flags + SLOT * 128;         // packed 4B flags
    int* f_oth = flags + (1 - SLOT) * 128;

    // LDS control
    volatile int* condA = (volatile int*)(lds + 131072);
    volatile int* condB = (volatile int*)(lds + 131076);
    volatile int* ctrs  = (volatile int*)(lds + 131080);   // 8 wave counters

    // LDS overlay (post-join): red [0,32K), r2b [32K,48K), gf [48K,~66K)
    float* red = (float*)lds;
    float* r2b = (float*)(lds + 32768);
    float* gf  = (float*)(lds + 49152);

    const int rw_ = lane >> 3;
    const int ss_ = (lane & 7) ^ rw_;        // pre-swizzled source 16B slot

    if (tid == 0) { *condA = -1; *condB = -1; }
    if (tid < 8) ctrs[tid] = 0;
    __syncthreads();

#pragma unroll 1
    for (int p = 0; p <= T_; ++p) {
        const bool active = SLOT ? (p >= 1) : (p < T_);
        const int tau = SLOT ? p - 1 : p;

        const f16* srcA = nullptr; size_t strA = 0; const f16* srcB = nullptr; f16* hout = nullptr;
        if (active) {
            if (SLOT == 0) {
                srcA = xh + (size_t)tau * I_;  strA = (size_t)T_ * I_;
                srcB = h0 + (size_t)((p + 3) & 3) * BH;     // h0[p-1]
                hout = h0 + (size_t)(p & 3) * BH;           // h0[p]
            } else {
                srcA = h0 + (size_t)((p + 3) & 3) * BH;  strA = H_;   // h0[p-1]
                srcB = h1 + (size_t)((p + 3) & 3) * BH;               // h1[p-2] (4-buf)
                hout = h1 + (size_t)(p & 3) * BH;                     // h1[p-1]
            }
        }

        auto issue = [&](int r) {
            const int kc = kw * KW + r * 64;
            const f16* base; size_t str; int koff; bool coh;
            if (kc < K0) { base = srcA; str = strA; koff = kc; coh = (SLOT == 1); }
            else         { base = srcB; str = (size_t)H_; koff = kc - K0; coh = true; }
            char* dbase = lds + kw * 32768 + (r & 3) * 8192 + nw * 4096;
#pragma unroll
            for (int i = 0; i < 4; ++i) {
                const int rl = rbase + nw * 32 + i * 8 + rw_;
                const f16* gp = base + (size_t)rl * str + koff + ss_ * 8;
                if (coh) gl_lds16_coh(gp, dbase + i * 1024);
                else     gl_lds16(gp, dbase + i * 1024);
            }
        };

        if (active) {
            // ---- pre-gate prefetch of x-only rounds (slot0) ----
            unsigned premask = 0;
            if (SLOT == 0) {
#pragma unroll
                for (int r = 0; r < 3; ++r)
                    if (kw * KW + r * 64 + 64 <= K0) { issue(r); premask |= 1u << r; }
            }

            // ---- per-wave gating ----
            if (SLOT == 0) {
                if (wave == 0) {
                    pollwait(f_oth, p - 2, lane);            // h0 buffer-reuse slack
                    if (lane == 0) { asm volatile("" ::: "memory"); *condB = p; }
                } else if (wave == 2) {
                    pollwait(f_own, p, lane);                // h0[p-1] fresh (phase p-1 done)
                    if (lane == 0) { asm volatile("" ::: "memory"); *condA = p; }
                } else if (wave >= 3) {
                    while (*condA < p) __builtin_amdgcn_s_sleep(1);
                    asm volatile("" ::: "memory");
                }   // wave1: free (x-only)
            } else {
                if (wave == 0) {
                    pollwait(f_oth, p, lane);                // h0[p-1] fresh from slot0
                    if (lane == 0) { asm volatile("" ::: "memory"); *condA = p; }
                } else if (wave <= 3) {
                    while (*condA < p) __builtin_amdgcn_s_sleep(1);
                    asm volatile("" ::: "memory");
                } else if (wave == 4) {
                    pollwait(f_own, p, lane);                // h1[p-2] fresh (produced @p-1!)
                    if (lane == 0) { asm volatile("" ::: "memory"); *condB = p; }
                } else {
                    while (*condB < p) __builtin_amdgcn_s_sleep(1);
                    asm volatile("" ::: "memory");
                }
            }
            __builtin_amdgcn_sched_barrier(0);

            // ---- remaining prologue ----
#pragma unroll
            for (int r = 0; r < 3; ++r)
                if (!(premask & (1u << r))) issue(r);

            v16f acc0 = {}, acc1 = {};

            // ---- K-loop: depth-3 counted vmcnt, pair handshake, no WG barrier ----
#pragma unroll
            for (int r = 0; r < NR; ++r) {
                if (r + 2 < NR)      asm volatile("s_waitcnt vmcnt(8)" ::: "memory");
                else if (r + 1 < NR) asm volatile("s_waitcnt vmcnt(4)" ::: "memory");
                else                 asm volatile("s_waitcnt vmcnt(0)" ::: "memory");
                asm volatile("s_waitcnt lgkmcnt(0)" ::: "memory");
                const int hv = p * 16 + r + 1;               // monotone handshake value
                if (lane == 0) ctrs[wave] = hv;
                {
                    volatile int* pc = ctrs + (wave ^ 1);
                    while (*pc < hv) { }
                }
                asm volatile("" ::: "memory");
                __builtin_amdgcn_sched_barrier(0);
                const char* sb = lds + kw * 32768 + (r & 3) * 8192;
#pragma unroll
                for (int ks = 0; ks < 4; ++ks) {
                    const int qo = (((ks * 2 + khi) ^ (l31 & 7)) << 4);
                    const v8h a0 = *(const v8h*)(sb + l31 * 128 + qo);
                    const v8h a1 = *(const v8h*)(sb + (32 + l31) * 128 + qo);
                    __builtin_amdgcn_s_setprio(1);
                    acc0 = __builtin_amdgcn_mfma_f32_32x32x16_f16(a0, wfrag[r * 4 + ks], acc0, 0, 0, 0);
                    acc1 = __builtin_amdgcn_mfma_f32_32x32x16_f16(a1, wfrag[r * 4 + ks], acc1, 0, 0, 0);
                    __builtin_amdgcn_s_setprio(0);
                }
                if (r + 3 < NR) issue(r + 3);
            }
            __syncthreads();   // join all waves; rings idle -> overlay safe

            // ---- kw-partial reduction: 4 -> 2 -> 1 (overlaid LDS) ----
            if (kw >= 2) {
                float* rg = red + ((kw - 2) * 2 + nw) * 2048;
#pragma unroll
                for (int j = 0; j < 16; ++j) {
                    rg[j * 64 + lane] = acc0[j];
                    rg[(16 + j) * 64 + lane] = acc1[j];
                }
            }
            __syncthreads();
            if (kw < 2) {
                const float* rg = red + (kw * 2 + nw) * 2048;
#pragma unroll
                for (int j = 0; j < 16; ++j) {
                    acc0[j] += rg[j * 64 + lane];
                    acc1[j] += rg[(16 + j) * 64 + lane];
                }
                if (kw == 1) {
                    float* rr = r2b + nw * 2048;
#pragma unroll
                    for (int j = 0; j < 16; ++j) {
                        rr[j * 64 + lane] = acc0[j];
                        rr[(16 + j) * 64 + lane] = acc1[j];
                    }
                }
            }
            __syncthreads();
            if (kw == 0) {
                const float* rr = r2b + nw * 2048;
#pragma unroll
                for (int j = 0; j < 16; ++j) {
                    const int row = (j & 3) + 8 * (j >> 2) + 4 * khi;
                    gf[row * 68 + nw * 32 + l31] = acc0[j] + rr[j * 64 + lane];
                    gf[(32 + row) * 68 + nw * 32 + l31] = acc1[j] + rr[(16 + j) * 64 + lane];
                }
            }
            __syncthreads();

            // ---- fused cell update: 2 cells/thread, c in registers ----
            {
                const float* g0 = gf + urow * 68 + un;
                const float xi0 = g0[0] + bI.x,  xi1 = g0[1] + bI.y;
                const float xf0 = g0[16] + bF.x, xf1 = g0[17] + bF.y;
                const float xg0 = g0[32] + bG.x, xg1 = g0[33] + bG.y;
                const float xo0 = g0[48] + bO.x, xo1 = g0[49] + bO.y;
                const float cn0 = fsigmoid(xf0) * c0r + fsigmoid(xi0) * ftanh(xg0);
                const float cn1 = fsigmoid(xf1) * c1r + fsigmoid(xi1) * ftanh(xg1);
                const float hn0 = fsigmoid(xo0) * ftanh(cn0);
                const float hn1 = fsigmoid(xo1) * ftanh(cn1);
                c0r = cn0; c1r = cn1;
                union { v2h h2; unsigned u; } cv;
                cv.h2[0] = (f16)hn0; cv.h2[1] = (f16)hn1;
                unsigned* hp = (unsigned*)(hout + (size_t)(rbase + urow) * H_ + n0 + un);
                asm volatile("global_store_dword %0, %1, off sc0 sc1" :: "v"(hp), "v"(cv.u) : "memory");
                if (SLOT == 1) {
                    float2 yv; yv.x = hn0; yv.y = hn1;
                    *(float2*)(out + ((size_t)(rbase + urow) * T_ + tau) * H_ + n0 + un) = yv;
                }
            }
        }

        // ---- arrive: drain stores, join, publish flag ----
        asm volatile("s_waitcnt vmcnt(0)" ::: "memory");
        __syncthreads();
        if (tid == 0) {
            int v = p + 1;
            int* fp = f_own + widx128;
            asm volatile("global_store_dword %0, %1, off sc0 sc1" :: "v"(fp), "v"(v) : "memory");
        }
    }
}

__global__ __launch_bounds__(512, 2) void lstm_persist7(
    const f16* __restrict__ xh,
    const f16* __restrict__ w0i, const f16* __restrict__ w0h,
    const f16* __restrict__ w1i, const f16* __restrict__ w1h,
    const float* __restrict__ bs0, const float* __restrict__ bs1,
    f16* __restrict__ h0, f16* __restrict__ h1, float* __restrict__ out,
    int* flags)
{
    __shared__ __align__(16) char lds[131200];
    const int bx = blockIdx.x;
    const int slot = bx & 1;
    const int mh = (bx >> 1) & 1;
    const int tile = bx >> 2;
    const int widx128 = mh * 64 + tile;
    if (slot == 0)
        run_slot5<0>(mh, tile, widx128, xh, w0i, w0h, bs0, h0, h1, out, flags, lds);
    else
        run_slot5<1>(mh, tile, widx128, xh, w1i, w1h, bs1, h0, h1, out, flags, lds);
}

// ---------------- fp32 fallback (round-1 verified) ----------------
#define BM 64
#define NT 8

__global__ __launch_bounds__(256) void lstm_step(
    const float* __restrict__ A1, long a1_stride, int K1,
    const float* __restrict__ hprev,
    const float* __restrict__ Wih, const float* __restrict__ Whh,
    const float* __restrict__ bih, const float* __restrict__ bhh,
    float* __restrict__ cbuf, float* __restrict__ hout,
    float* yout, long y_stride)
{
    __shared__ float As[32][66];
    __shared__ float Ws[32][36];
    const int tid = threadIdx.x;
    const int n0 = blockIdx.x * NT;
    const int b0 = blockIdx.y * BM;
    const int tb = tid >> 3;
    const int tc = tid & 7;
    const int lr = tid >> 3;
    const int lk = tid & 7;
    const long wj = (long)(lr >> 3) * H_ + n0 + (lr & 7);
    float acc[2][4] = {{0.f, 0.f, 0.f, 0.f}, {0.f, 0.f, 0.f, 0.f}};
#pragma unroll 1
    for (int ph = 0; ph < 2; ++ph) {
        const float* Ap = (ph == 0) ? A1 : hprev;
        const long as = (ph == 0) ? a1_stride : (long)H_;
        const float* W = (ph == 0) ? Wih : Whh;
        const int K = (ph == 0) ? K1 : H_;
        const float* arow0 = Ap + (long)(b0 + lr) * as + 4 * lk;
        const float* arow1 = Ap + (long)(b0 + lr + 32) * as + 4 * lk;
        const float* wrow = W + wj * K + 4 * lk;
        float4 ra0 = *(const float4*)(arow0);
        float4 ra1 = *(const float4*)(arow1);
        float4 rw = *(const float4*)(wrow);
        for (int k0 = 0; k0 < K; k0 += 32) {
            __syncthreads();
            {
                const int kk = 4 * lk;
                As[kk + 0][lr] = ra0.x; As[kk + 1][lr] = ra0.y;
                As[kk + 2][lr] = ra0.z; As[kk + 3][lr] = ra0.w;
                As[kk + 0][lr + 32] = ra1.x; As[kk + 1][lr + 32] = ra1.y;
                As[kk + 2][lr + 32] = ra1.z; As[kk + 3][lr + 32] = ra1.w;
                Ws[kk + 0][lr] = rw.x; Ws[kk + 1][lr] = rw.y;
                Ws[kk + 2][lr] = rw.z; Ws[kk + 3][lr] = rw.w;
            }
            __syncthreads();
            const int kn = k0 + 32;
            if (kn < K) {
                ra0 = *(const float4*)(arow0 + kn);
                ra1 = *(const float4*)(arow1 + kn);
                rw = *(const float4*)(wrow + kn);
            }
#pragma unroll
            for (int k = 0; k < 32; ++k) {
                float2 a = *(const float2*)&As[k][2 * tb];
                float4 w = *(const float4*)&Ws[k][4 * tc];
                acc[0][0] = fmaf(a.x, w.x, acc[0][0]);
                acc[0][1] = fmaf(a.x, w.y, acc[0][1]);
                acc[0][2] = fmaf(a.x, w.z, acc[0][2]);
                acc[0][3] = fmaf(a.x, w.w, acc[0][3]);
                acc[1][0] = fmaf(a.y, w.x, acc[1][0]);
                acc[1][1] = fmaf(a.y, w.y, acc[1][1]);
                acc[1][2] = fmaf(a.y, w.z, acc[1][2]);
                acc[1][3] = fmaf(a.y, w.w, acc[1][3]);
            }
        }
    }
    __syncthreads();
    float* gsf = &As[0][0];
#pragma unroll
    for (int bi = 0; bi < 2; ++bi)
#pragma unroll
        for (int ci = 0; ci < 4; ++ci)
            gsf[(2 * tb + bi) * 33 + 4 * tc + ci] = acc[bi][ci];
    __syncthreads();
    const int dn = tid & 7;
    const int bq = tid >> 3;
    const int n = n0 + dn;
#pragma unroll
    for (int s = 0; s < 2; ++s) {
        const int b = bq + 32 * s;
        float xi = gsf[b * 33 + dn] + bih[n] + bhh[n];
        float xf = gsf[b * 33 + 8 + dn] + bih[H_ + n] + bhh[H_ + n];
        float xg = gsf[b * 33 + 16 + dn] + bih[2 * H_ + n] + bhh[2 * H_ + n];
        float xo = gsf[b * 33 + 24 + dn] + bih[3 * H_ + n] + bhh[3 * H_ + n];
        const long idx = (long)(b0 + b) * H_ + n;
        const float c_old = cbuf[idx];
        const float cn = fsigmoid(xf) * c_old + fsigmoid(xi) * ftanh(xg);
        const float hn = fsigmoid(xo) * ftanh(cn);
        cbuf[idx] = cn;
        hout[idx] = hn;
        if (yout) yout[(long)(b0 + b) * y_stride + n] = hn;
    }
}

extern "C" void kernel_launch(void* const* d_in, const int* in_sizes, int n_in,
                              void* d_out, int out_size, void* d_ws, size_t ws_size,
                              hipStream_t stream) {
    const float* x = (const float*)d_in[0];
    const float* Wih0 = (const float*)d_in[1];
    const float* Whh0 = (const float*)d_in[2];
    const float* bih0 = (const float*)d_in[3];
    const float* bhh0 = (const float*)d_in[4];
    const float* Wih1 = (const float*)d_in[5];
    const float* Whh1 = (const float*)d_in[6];
    const float* bih1 = (const float*)d_in[7];
    const float* bhh1 = (const float*)d_in[8];
    float* out = (float*)d_out;

    const size_t BH = (size_t)B_ * H_;
    const size_t NX = (size_t)B_ * T_ * I_;
    const size_t NW0I = (size_t)4 * H_ * I_;
    const size_t NWH = (size_t)4 * H_ * H_;

    const size_t off_xh = 0;
    const size_t off_w0i = off_xh + NX * 2;
    const size_t off_w0h = off_w0i + NW0I * 2;
    const size_t off_w1i = off_w0h + NWH * 2;
    const size_t off_w1h = off_w1i + NWH * 2;
    const size_t off_bs0 = off_w1h + NWH * 2;
    const size_t off_bs1 = off_bs0 + 4 * H_ * 4;
    const size_t off_h0 = off_bs1 + 4 * H_ * 4;        // 4 buffers
    const size_t off_h1 = off_h0 + 4 * BH * 2;         // 4 buffers
    const size_t off_flags = off_h1 + 4 * BH * 2;      // 256 packed ints
    const size_t REQ = off_flags + 256 * 4;

    char* ws = (char*)d_ws;

    if (ws_size >= REQ) {
        f16* xh = (f16*)(ws + off_xh);
        f16* w0i = (f16*)(ws + off_w0i);
        f16* w0h = (f16*)(ws + off_w0h);
        f16* w1i = (f16*)(ws + off_w1i);
        f16* w1h = (f16*)(ws + off_w1h);
        float* bs0 = (float*)(ws + off_bs0);
        float* bs1 = (float*)(ws + off_bs1);
        f16* h0 = (f16*)(ws + off_h0);
        f16* h1 = (f16*)(ws + off_h1);
        int* flags = (int*)(ws + off_flags);

        // zero h0, h1, flags — contiguous tail
        hipMemsetAsync(ws + off_h0, 0, REQ - off_h0, stream);

        dim3 cb(256);
        k_f32_to_f16<<<2048, cb, 0, stream>>>(x, xh, (int)NX);
        k_f32_to_f16<<<2048, cb, 0, stream>>>(Wih0, w0i, (int)NW0I);
        k_f32_to_f16<<<2048, cb, 0, stream>>>(Whh0, w0h, (int)NWH);
        k_f32_to_f16<<<2048, cb, 0, stream>>>(Wih1, w1i, (int)NWH);
        k_f32_to_f16<<<2048, cb, 0, stream>>>(Whh1, w1h, (int)NWH);
        k_bias_sum<<<16, cb, 0, stream>>>(bih0, bhh0, bs0, 4 * H_);
        k_bias_sum<<<16, cb, 0, stream>>>(bih1, bhh1, bs1, 4 * H_);

        lstm_persist7<<<256, 512, 0, stream>>>(xh, w0i, w0h, w1i, w1h, bs0, bs1,
                                               h0, h1, out, flags);
        return;
    }

    // ---------- fp32 fallback ----------
    float* fws = (float*)d_ws;
    float* h0a = fws;
    float* h0b = fws + BH;
    float* c0 = fws + 2 * BH;
    float* h1a = fws + 3 * BH;
    float* h1b = fws + 4 * BH;
    float* c1 = fws + 5 * BH;
    hipMemsetAsync(d_ws, 0, 6 * BH * sizeof(float), stream);

    dim3 grid(H_ / NT, B_ / BM);
    dim3 block(256);
    for (int t = 0; t < T_; ++t) {
        float* h0in = (t & 1) ? h0b : h0a;
        float* h0out = (t & 1) ? h0a : h0b;
        float* h1in = (t & 1) ? h1b : h1a;
        float* h1out = (t & 1) ? h1a : h1b;
        lstm_step<<<grid, block, 0, stream>>>(
            x + (size_t)t * I_, (long)T_ * I_, I_,
            h0in, Wih0, Whh0, bih0, bhh0, c0, h0out, nullptr, 0);
        lstm_step<<<grid, block, 0, stream>>>(
            h0out, (long)H_, H_,
            h1in, Wih1, Whh1, bih1, bhh1, c1, h1out,
            out + (size_t)t * H_, (long)T_ * H_);
    }
}

// Round 12
// 2518.494 us; speedup vs baseline: 1.1176x; 1.1176x over previous
//
#include <hip/hip_runtime.h>

#define B_ 128
#define T_ 256
#define I_ 512
#define H_ 1024

typedef _Float16 f16;
typedef _Float16 v8h __attribute__((ext_vector_type(8)));
typedef _Float16 v2h __attribute__((ext_vector_type(2)));
typedef float v16f __attribute__((ext_vector_type(16)));
typedef int v4i __attribute__((ext_vector_type(4)));

__device__ __forceinline__ float fsigmoid(float x) { return 1.0f / (1.0f + __expf(-x)); }
__device__ __forceinline__ float ftanh(float x) { return 1.0f - 2.0f / (__expf(2.0f * x) + 1.0f); }

__device__ __forceinline__ void gl_lds16(const void* g, void* l) {
    __builtin_amdgcn_global_load_lds(
        (const __attribute__((address_space(1))) unsigned int*)g,
        (__attribute__((address_space(3))) unsigned int*)l, 16, 0, 0);
}
// device-coherent (SC0|SC1): read the coherence point (fresh h)
__device__ __forceinline__ void gl_lds16_coh(const void* g, void* l) {
    __builtin_amdgcn_global_load_lds(
        (const __attribute__((address_space(1))) unsigned int*)g,
        (__attribute__((address_space(3))) unsigned int*)l, 16, 0, 17);
}

// poll 128 packed flags (lanes 0..31 load dwordx4 each); returns when all >= tgt
__device__ __forceinline__ void pollwait(const int* base, int tgt, int lane) {
    if (tgt <= 0) return;
    for (;;) {
        bool ok = true;
        if (lane < 32) {
            v4i v;
            asm volatile("global_load_dwordx4 %0, %1, off sc0 sc1\n\ts_waitcnt vmcnt(0)"
                         : "=&v"(v) : "v"(base + lane * 4) : "memory");
            ok = (v[0] >= tgt) && (v[1] >= tgt) && (v[2] >= tgt) && (v[3] >= tgt);
        }
        if (__ballot(ok) == ~0ULL) return;
        __builtin_amdgcn_s_sleep(1);
    }
}

#define WAITV(n) asm volatile("s_waitcnt vmcnt(" #n ")" ::: "memory")
#define BARX { __builtin_amdgcn_s_barrier(); __builtin_amdgcn_sched_barrier(0); }

// ---------------- conversion kernels ----------------
__global__ void k_f32_to_f16(const float* __restrict__ in, f16* __restrict__ out, int n) {
    int i = blockIdx.x * blockDim.x + threadIdx.x;
    int st = gridDim.x * blockDim.x;
    for (; i < n; i += st) out[i] = (f16)in[i];
}
__global__ void k_bias_sum(const float* __restrict__ a, const float* __restrict__ b,
                           float* __restrict__ o, int n) {
    int i = blockIdx.x * blockDim.x + threadIdx.x;
    int st = gridDim.x * blockDim.x;
    for (; i < n; i += st) o[i] = a[i] + b[i];
}

// ---------------- persistent 2-pipeline LSTM, R8 skeleton + reordered windows ----------------
// 256 WGs x 512 threads, 1 WG/CU. bx = tile*4 + mh*2 + slot.
// slot0 phase p: layer0[t=p]; slot1 phase p: layer1[t=p-1]. h0,h1 both x4 buffers.
// FLAG SEMANTICS: flag published at end of phase p is p+1; flag>=k <=> phase k-1 done.
// Window remap (uniform per wave): independent source rounds FIRST:
//   slot0: rounds 0-1 = x (free), rounds 2-5 = h0[p-1] (gate own>=p mid-loop)
//   slot1: rounds 0-3 = h1[p-2] (gate own>=p pre-loop), rounds 4-7 = h0[p-1] (gate oth>=p mid-loop)
// slot0's h0-write safety (oth>=p-2) checked pre-epilogue (overlaps whole K-loop).
// K-loop: WG-wide s_barrier per round (R8-proven), ring-4 x 8KB per kw window.
template <int SLOT>
__device__ void run_slot8(int mh, int tile, int widx128,
                          const f16* __restrict__ xh,
                          const f16* __restrict__ wi, const f16* __restrict__ wh,
                          const float* __restrict__ bs,
                          f16* __restrict__ h0, f16* __restrict__ h1,
                          float* __restrict__ out, int* flags, char* lds)
{
    constexpr int NKS = SLOT ? 32 : 24;     // W fragments per wave
    const size_t BH = (size_t)B_ * H_;

    const int tid = threadIdx.x;
    const int wave = tid >> 6;
    const int lane = tid & 63;
    const int l31 = lane & 31, khi = lane >> 5;
    const int nw = wave & 1, kw = wave >> 1;
    const int n0 = tile * 16;
    const int rbase = mh * 64;

    // ---- W fragments -> registers (once), matching the reordered windows ----
    const int gcl = nw * 32 + l31;
    const size_t gr = (size_t)(gcl >> 4) * H_ + n0 + (gcl & 15);
    v8h wfrag[NKS];
#pragma unroll
    for (int s = 0; s < NKS; ++s) {
        const f16* p;
        if (SLOT == 0) {
            p = (s < 8) ? (wi + gr * 512 + kw * 128 + s * 16 + khi * 8)
                        : (wh + gr * 1024 + kw * 256 + (s - 8) * 16 + khi * 8);
        } else {
            p = (s < 16) ? (wh + gr * 1024 + kw * 256 + s * 16 + khi * 8)
                         : (wi + gr * 1024 + kw * 256 + (s - 16) * 16 + khi * 8);
        }
        wfrag[s] = *(const v8h*)p;
    }

    // ---- per-thread cell state + biases (2 cells) ----
    const int urow = tid >> 3;
    const int un = (tid & 7) * 2;
    const float2 bI = *(const float2*)(bs + 0 * H_ + n0 + un);
    const float2 bF = *(const float2*)(bs + 1 * H_ + n0 + un);
    const float2 bG = *(const float2*)(bs + 2 * H_ + n0 + un);
    const float2 bO = *(const float2*)(bs + 3 * H_ + n0 + un);
    float c0r = 0.f, c1r = 0.f;

    int* f_own = flags + SLOT * 128;         // packed 4B flags
    int* f_oth = flags + (1 - SLOT) * 128;

    float* gf = (float*)(lds + 49152);       // [64][68] f32 (post-join overlay)

    const int rw_ = lane >> 3;
    const int ss_ = (lane & 7) ^ rw_;        // pre-swizzled source 16B slot

#pragma unroll 1
    for (int p = 0; p <= T_; ++p) {
        const bool active = SLOT ? (p >= 1) : (p < T_);
        const int tau = SLOT ? p - 1 : p;

        const f16* srcA = nullptr; size_t strA = 0; const f16* srcB = nullptr; f16* hout = nullptr;
        if (active) {
            if (SLOT == 0) {
                srcA = xh + (size_t)tau * I_;  strA = (size_t)T_ * I_;   // x
                srcB = h0 + (size_t)((p + 3) & 3) * BH;                  // h0[p-1]
                hout = h0 + (size_t)(p & 3) * BH;                        // h0[p]
            } else {
                srcA = h0 + (size_t)((p + 3) & 3) * BH;                  // h0[p-1]
                srcB = h1 + (size_t)((p + 3) & 3) * BH;                  // h1[p-2]
                hout = h1 + (size_t)(p & 3) * BH;                        // h1[p-1]
            }
        }

        auto issue = [&](int r) {
            const f16* base; size_t str; int koff; bool coh;
            if (SLOT == 0) {
                if (r < 2) { base = srcA; str = strA;      koff = kw * 128 + r * 64;       coh = false; }
                else       { base = srcB; str = (size_t)H_; koff = kw * 256 + (r - 2) * 64; coh = true; }
            } else {
                if (r < 4) { base = srcB; str = (size_t)H_; koff = kw * 256 + r * 64;       coh = true; }
                else       { base = srcA; str = (size_t)H_; koff = kw * 256 + (r - 4) * 64; coh = true; }
            }
            char* dbase = lds + kw * 32768 + (r & 3) * 8192 + nw * 4096;
#pragma unroll
            for (int i = 0; i < 4; ++i) {
                const int rl = rbase + nw * 32 + i * 8 + rw_;
                const f16* gp = base + (size_t)rl * str + koff + ss_ * 8;
                if (coh) gl_lds16_coh(gp, dbase + i * 1024);
                else     gl_lds16(gp, dbase + i * 1024);
            }
        };

        v16f acc0 = {}, acc1 = {};

        auto compute = [&](int r) {
            const char* sb = lds + kw * 32768 + (r & 3) * 8192;
#pragma unroll
            for (int ks = 0; ks < 4; ++ks) {
                const int qo = (((ks * 2 + khi) ^ (l31 & 7)) << 4);
                const v8h a0 = *(const v8h*)(sb + l31 * 128 + qo);
                const v8h a1 = *(const v8h*)(sb + (32 + l31) * 128 + qo);
                __builtin_amdgcn_s_setprio(1);
                acc0 = __builtin_amdgcn_mfma_f32_32x32x16_f16(a0, wfrag[r * 4 + ks], acc0, 0, 0, 0);
                acc1 = __builtin_amdgcn_mfma_f32_32x32x16_f16(a1, wfrag[r * 4 + ks], acc1, 0, 0, 0);
                __builtin_amdgcn_s_setprio(0);
            }
        };

        if (active) {
            if (SLOT == 0) {
                // ---- x rounds (no gate) ----
                issue(0); issue(1);
                WAITV(4); BARX; compute(0);
                WAITV(0); BARX; compute(1);
                // ---- gate: h0[p-1] fresh (slot0 peers done phase p-1) ----
                if (wave == 0) pollwait(f_own, p, lane);
                BARX;
                issue(2); issue(3); issue(4);
                WAITV(8); BARX; compute(2); issue(5);
                WAITV(8); BARX; compute(3);
                WAITV(4); BARX; compute(4);
                WAITV(0); BARX; compute(5);
            } else {
                // ---- pre-gate: h1[p-2] fresh + h1-buffer safety (own peers done p-1) ----
                if (wave == 4) pollwait(f_own, p, lane);
                __syncthreads();
                issue(0); issue(1); issue(2);
                WAITV(8); BARX; compute(0); issue(3);
                WAITV(8); BARX; compute(1);
                // ---- cross-gate: h0[p-1] fresh from slot0 ----
                if (wave == 0) pollwait(f_oth, p, lane);
                BARX;
                issue(4);
                WAITV(8); BARX; compute(2); issue(5);
                WAITV(8); BARX; compute(3); issue(6);
                WAITV(8); BARX; compute(4); issue(7);
                WAITV(8); BARX; compute(5);
                WAITV(4); BARX; compute(6);
                WAITV(0); BARX; compute(7);
            }
            __syncthreads();   // join; rings idle -> overlay safe

            // ---- 2-stage reduction: 6 waves write partials; kw0 pair sums -> gf ----
            if (kw >= 1) {
                float* rg = (float*)lds + ((kw - 1) * 2 + nw) * 2048;
#pragma unroll
                for (int j = 0; j < 16; ++j) {
                    rg[j * 64 + lane] = acc0[j];
                    rg[(16 + j) * 64 + lane] = acc1[j];
                }
            }
            __syncthreads();
            if (kw == 0) {
                const float* r0 = (float*)lds + (0 + nw) * 2048;
                const float* r1 = (float*)lds + (2 + nw) * 2048;
                const float* r2 = (float*)lds + (4 + nw) * 2048;
#pragma unroll
                for (int j = 0; j < 16; ++j) {
                    const float s0 = acc0[j] + r0[j * 64 + lane] + r1[j * 64 + lane] + r2[j * 64 + lane];
                    const float s1 = acc1[j] + r0[(16 + j) * 64 + lane] + r1[(16 + j) * 64 + lane] + r2[(16 + j) * 64 + lane];
                    const int row = (j & 3) + 8 * (j >> 2) + 4 * khi;
                    gf[row * 68 + nw * 32 + l31] = s0;
                    gf[(32 + row) * 68 + nw * 32 + l31] = s1;
                }
            }
            __syncthreads();

            // ---- slot0 pre-epilogue safety: slot1 readers of h0[p-4] done (huge slack) ----
            if (SLOT == 0) {
                if (wave == 0) pollwait(f_oth, p - 2, lane);
                __syncthreads();
            }

            // ---- fused cell update: 2 cells/thread, c in registers ----
            {
                const float* g0 = gf + urow * 68 + un;
                const float xi0 = g0[0] + bI.x,  xi1 = g0[1] + bI.y;
                const float xf0 = g0[16] + bF.x, xf1 = g0[17] + bF.y;
                const float xg0 = g0[32] + bG.x, xg1 = g0[33] + bG.y;
                const float xo0 = g0[48] + bO.x, xo1 = g0[49] + bO.y;
                const float cn0 = fsigmoid(xf0) * c0r + fsigmoid(xi0) * ftanh(xg0);
                const float cn1 = fsigmoid(xf1) * c1r + fsigmoid(xi1) * ftanh(xg1);
                const float hn0 = fsigmoid(xo0) * ftanh(cn0);
                const float hn1 = fsigmoid(xo1) * ftanh(cn1);
                c0r = cn0; c1r = cn1;
                union { v2h h2; unsigned u; } cv;
                cv.h2[0] = (f16)hn0; cv.h2[1] = (f16)hn1;
                unsigned* hp = (unsigned*)(hout + (size_t)(rbase + urow) * H_ + n0 + un);
                asm volatile("global_store_dword %0, %1, off sc0 sc1" :: "v"(hp), "v"(cv.u) : "memory");
                if (SLOT == 1) {
                    float2 yv; yv.x = hn0; yv.y = hn1;
                    *(float2*)(out + ((size_t)(rbase + urow) * T_ + tau) * H_ + n0 + un) = yv;
                }
            }
        }

        // ---- arrive: drain stores, join, publish flag ----
        asm volatile("s_waitcnt vmcnt(0)" ::: "memory");
        __syncthreads();
        if (tid == 0) {
            int v = p + 1;
            int* fp = f_own + widx128;
            asm volatile("global_store_dword %0, %1, off sc0 sc1" :: "v"(fp), "v"(v) : "memory");
        }
    }
}

__global__ __launch_bounds__(512, 2) void lstm_persist8(
    const f16* __restrict__ xh,
    const f16* __restrict__ w0i, const f16* __restrict__ w0h,
    const f16* __restrict__ w1i, const f16* __restrict__ w1h,
    const float* __restrict__ bs0, const float* __restrict__ bs1,
    f16* __restrict__ h0, f16* __restrict__ h1, float* __restrict__ out,
    int* flags)
{
    __shared__ __align__(16) char lds[131072];
    const int bx = blockIdx.x;
    const int slot = bx & 1;
    const int mh = (bx >> 1) & 1;
    const int tile = bx >> 2;
    const int widx128 = mh * 64 + tile;
    if (slot == 0)
        run_slot8<0>(mh, tile, widx128, xh, w0i, w0h, bs0, h0, h1, out, flags, lds);
    else
        run_slot8<1>(mh, tile, widx128, xh, w1i, w1h, bs1, h0, h1, out, flags, lds);
}

// ---------------- fp32 fallback (round-1 verified) ----------------
#define BM 64
#define NT 8

__global__ __launch_bounds__(256) void lstm_step(
    const float* __restrict__ A1, long a1_stride, int K1,
    const float* __restrict__ hprev,
    const float* __restrict__ Wih, const float* __restrict__ Whh,
    const float* __restrict__ bih, const float* __restrict__ bhh,
    float* __restrict__ cbuf, float* __restrict__ hout,
    float* yout, long y_stride)
{
    __shared__ float As[32][66];
    __shared__ float Ws[32][36];
    const int tid = threadIdx.x;
    const int n0 = blockIdx.x * NT;
    const int b0 = blockIdx.y * BM;
    const int tb = tid >> 3;
    const int tc = tid & 7;
    const int lr = tid >> 3;
    const int lk = tid & 7;
    const long wj = (long)(lr >> 3) * H_ + n0 + (lr & 7);
    float acc[2][4] = {{0.f, 0.f, 0.f, 0.f}, {0.f, 0.f, 0.f, 0.f}};
#pragma unroll 1
    for (int ph = 0; ph < 2; ++ph) {
        const float* Ap = (ph == 0) ? A1 : hprev;
        const long as = (ph == 0) ? a1_stride : (long)H_;
        const float* W = (ph == 0) ? Wih : Whh;
        const int K = (ph == 0) ? K1 : H_;
        const float* arow0 = Ap + (long)(b0 + lr) * as + 4 * lk;
        const float* arow1 = Ap + (long)(b0 + lr + 32) * as + 4 * lk;
        const float* wrow = W + wj * K + 4 * lk;
        float4 ra0 = *(const float4*)(arow0);
        float4 ra1 = *(const float4*)(arow1);
        float4 rw = *(const float4*)(wrow);
        for (int k0 = 0; k0 < K; k0 += 32) {
            __syncthreads();
            {
                const int kk = 4 * lk;
                As[kk + 0][lr] = ra0.x; As[kk + 1][lr] = ra0.y;
                As[kk + 2][lr] = ra0.z; As[kk + 3][lr] = ra0.w;
                As[kk + 0][lr + 32] = ra1.x; As[kk + 1][lr + 32] = ra1.y;
                As[kk + 2][lr + 32] = ra1.z; As[kk + 3][lr + 32] = ra1.w;
                Ws[kk + 0][lr] = rw.x; Ws[kk + 1][lr] = rw.y;
                Ws[kk + 2][lr] = rw.z; Ws[kk + 3][lr] = rw.w;
            }
            __syncthreads();
            const int kn = k0 + 32;
            if (kn < K) {
                ra0 = *(const float4*)(arow0 + kn);
                ra1 = *(const float4*)(arow1 + kn);
                rw = *(const float4*)(wrow + kn);
            }
#pragma unroll
            for (int k = 0; k < 32; ++k) {
                float2 a = *(const float2*)&As[k][2 * tb];
                float4 w = *(const float4*)&Ws[k][4 * tc];
                acc[0][0] = fmaf(a.x, w.x, acc[0][0]);
                acc[0][1] = fmaf(a.x, w.y, acc[0][1]);
                acc[0][2] = fmaf(a.x, w.z, acc[0][2]);
                acc[0][3] = fmaf(a.x, w.w, acc[0][3]);
                acc[1][0] = fmaf(a.y, w.x, acc[1][0]);
                acc[1][1] = fmaf(a.y, w.y, acc[1][1]);
                acc[1][2] = fmaf(a.y, w.z, acc[1][2]);
                acc[1][3] = fmaf(a.y, w.w, acc[1][3]);
            }
        }
    }
    __syncthreads();
    float* gsf = &As[0][0];
#pragma unroll
    for (int bi = 0; bi < 2; ++bi)
#pragma unroll
        for (int ci = 0; ci < 4; ++ci)
            gsf[(2 * tb + bi) * 33 + 4 * tc + ci] = acc[bi][ci];
    __syncthreads();
    const int dn = tid & 7;
    const int bq = tid >> 3;
    const int n = n0 + dn;
#pragma unroll
    for (int s = 0; s < 2; ++s) {
        const int b = bq + 32 * s;
        float xi = gsf[b * 33 + dn] + bih[n] + bhh[n];
        float xf = gsf[b * 33 + 8 + dn] + bih[H_ + n] + bhh[H_ + n];
        float xg = gsf[b * 33 + 16 + dn] + bih[2 * H_ + n] + bhh[2 * H_ + n];
        float xo = gsf[b * 33 + 24 + dn] + bih[3 * H_ + n] + bhh[3 * H_ + n];
        const long idx = (long)(b0 + b) * H_ + n;
        const float c_old = cbuf[idx];
        const float cn = fsigmoid(xf) * c_old + fsigmoid(xi) * ftanh(xg);
        const float hn = fsigmoid(xo) * ftanh(cn);
        cbuf[idx] = cn;
        hout[idx] = hn;
        if (yout) yout[(long)(b0 + b) * y_stride + n] = hn;
    }
}

extern "C" void kernel_launch(void* const* d_in, const int* in_sizes, int n_in,
                              void* d_out, int out_size, void* d_ws, size_t ws_size,
                              hipStream_t stream) {
    const float* x = (const float*)d_in[0];
    const float* Wih0 = (const float*)d_in[1];
    const float* Whh0 = (const float*)d_in[2];
    const float* bih0 = (const float*)d_in[3];
    const float* bhh0 = (const float*)d_in[4];
    const float* Wih1 = (const float*)d_in[5];
    const float* Whh1 = (const float*)d_in[6];
    const float* bih1 = (const float*)d_in[7];
    const float* bhh1 = (const float*)d_in[8];
    float* out = (float*)d_out;

    const size_t BH = (size_t)B_ * H_;
    const size_t NX = (size_t)B_ * T_ * I_;
    const size_t NW0I = (size_t)4 * H_ * I_;
    const size_t NWH = (size_t)4 * H_ * H_;

    const size_t off_xh = 0;
    const size_t off_w0i = off_xh + NX * 2;
    const size_t off_w0h = off_w0i + NW0I * 2;
    const size_t off_w1i = off_w0h + NWH * 2;
    const size_t off_w1h = off_w1i + NWH * 2;
    const size_t off_bs0 = off_w1h + NWH * 2;
    const size_t off_bs1 = off_bs0 + 4 * H_ * 4;
    const size_t off_h0 = off_bs1 + 4 * H_ * 4;        // 4 buffers
    const size_t off_h1 = off_h0 + 4 * BH * 2;         // 4 buffers
    const size_t off_flags = off_h1 + 4 * BH * 2;      // 256 packed ints
    const size_t REQ = off_flags + 256 * 4;

    char* ws = (char*)d_ws;

    if (ws_size >= REQ) {
        f16* xh = (f16*)(ws + off_xh);
        f16* w0i = (f16*)(ws + off_w0i);
        f16* w0h = (f16*)(ws + off_w0h);
        f16* w1i = (f16*)(ws + off_w1i);
        f16* w1h = (f16*)(ws + off_w1h);
        float* bs0 = (float*)(ws + off_bs0);
        float* bs1 = (float*)(ws + off_bs1);
        f16* h0 = (f16*)(ws + off_h0);
        f16* h1 = (f16*)(ws + off_h1);
        int* flags = (int*)(ws + off_flags);

        // zero h0, h1, flags — contiguous tail
        hipMemsetAsync(ws + off_h0, 0, REQ - off_h0, stream);

        dim3 cb(256);
        k_f32_to_f16<<<2048, cb, 0, stream>>>(x, xh, (int)NX);
        k_f32_to_f16<<<2048, cb, 0, stream>>>(Wih0, w0i, (int)NW0I);
        k_f32_to_f16<<<2048, cb, 0, stream>>>(Whh0, w0h, (int)NWH);
        k_f32_to_f16<<<2048, cb, 0, stream>>>(Wih1, w1i, (int)NWH);
        k_f32_to_f16<<<2048, cb, 0, stream>>>(Whh1, w1h, (int)NWH);
        k_bias_sum<<<16, cb, 0, stream>>>(bih0, bhh0, bs0, 4 * H_);
        k_bias_sum<<<16, cb, 0, stream>>>(bih1, bhh1, bs1, 4 * H_);

        lstm_persist8<<<256, 512, 0, stream>>>(xh, w0i, w0h, w1i, w1h, bs0, bs1,
                                               h0, h1, out, flags);
        return;
    }

    // ---------- fp32 fallback ----------
    float* fws = (float*)d_ws;
    float* h0a = fws;
    float* h0b = fws + BH;
    float* c0 = fws + 2 * BH;
    float* h1a = fws + 3 * BH;
    float* h1b = fws + 4 * BH;
    float* c1 = fws + 5 * BH;
    hipMemsetAsync(d_ws, 0, 6 * BH * sizeof(float), stream);

    dim3 grid(H_ / NT, B_ / BM);
    dim3 block(256);
    for (int t = 0; t < T_; ++t) {
        float* h0in = (t & 1) ? h0b : h0a;
        float* h0out = (t & 1) ? h0a : h0b;
        float* h1in = (t & 1) ? h1b : h1a;
        float* h1out = (t & 1) ? h1a : h1b;
        lstm_step<<<grid, block, 0, stream>>>(
            x + (size_t)t * I_, (long)T_ * I_, I_,
            h0in, Wih0, Whh0, bih0, bhh0, c0, h0out, nullptr, 0);
        lstm_step<<<grid, block, 0, stream>>>(
            h0out, (long)H_, H_,
            h1in, Wih1, Whh1, bih1, bhh1, c1, h1out,
            out + (size_t)t * H_, (long)T_ * H_);
    }
}

// Round 13
// 2238.907 us; speedup vs baseline: 1.2572x; 1.1249x over previous
//
#include <hip/hip_runtime.h>

#define B_ 128
#define T_ 256
#define I_ 512
#define H_ 1024

typedef _Float16 f16;
typedef _Float16 v8h __attribute__((ext_vector_type(8)));
typedef _Float16 v2h __attribute__((ext_vector_type(2)));
typedef float v16f __attribute__((ext_vector_type(16)));
typedef int v4i __attribute__((ext_vector_type(4)));

__device__ __forceinline__ float fsigmoid(float x) { return 1.0f / (1.0f + __expf(-x)); }
__device__ __forceinline__ float ftanh(float x) { return 1.0f - 2.0f / (__expf(2.0f * x) + 1.0f); }

__device__ __forceinline__ void gl_lds16(const void* g, void* l) {
    __builtin_amdgcn_global_load_lds(
        (const __attribute__((address_space(1))) unsigned int*)g,
        (__attribute__((address_space(3))) unsigned int*)l, 16, 0, 0);
}
// device-coherent (SC0|SC1): read the coherence point (fresh h)
__device__ __forceinline__ void gl_lds16_coh(const void* g, void* l) {
    __builtin_amdgcn_global_load_lds(
        (const __attribute__((address_space(1))) unsigned int*)g,
        (__attribute__((address_space(3))) unsigned int*)l, 16, 0, 17);
}

// Dual-condition poll: lanes 0-15 cover 64 flags at baseA (>= tA),
// lanes 16-31 cover 64 flags at baseB (>= tB). Low-congestion: 32 requests/iter.
__device__ __forceinline__ void pollwait2(const int* baseA, int tA,
                                          const int* baseB, int tB, int lane) {
    if (tA <= 0 && tB <= 0) return;
    for (;;) {
        bool ok = true;
        if (lane < 32) {
            const int* b = (lane < 16) ? baseA : baseB;
            const int t = (lane < 16) ? tA : tB;
            v4i v;
            asm volatile("global_load_dwordx4 %0, %1, off sc0 sc1\n\ts_waitcnt vmcnt(0)"
                         : "=&v"(v) : "v"(b + (lane & 15) * 4) : "memory");
            ok = (t <= 0) || ((v[0] >= t) && (v[1] >= t) && (v[2] >= t) && (v[3] >= t));
        }
        if (__ballot(ok) == ~0ULL) return;
        __builtin_amdgcn_s_sleep(4);
    }
}

#define WAITV(n) asm volatile("s_waitcnt vmcnt(" #n ")" ::: "memory")
#define BARX { __builtin_amdgcn_s_barrier(); __builtin_amdgcn_sched_barrier(0); }

// ---------------- conversion kernels ----------------
__global__ void k_f32_to_f16(const float* __restrict__ in, f16* __restrict__ out, int n) {
    int i = blockIdx.x * blockDim.x + threadIdx.x;
    int st = gridDim.x * blockDim.x;
    for (; i < n; i += st) out[i] = (f16)in[i];
}
__global__ void k_bias_sum(const float* __restrict__ a, const float* __restrict__ b,
                           float* __restrict__ o, int n) {
    int i = blockIdx.x * blockDim.x + threadIdx.x;
    int st = gridDim.x * blockDim.x;
    for (; i < n; i += st) o[i] = a[i] + b[i];
}

// ---------------- persistent 2-pipeline LSTM (R8 skeleton, depth-4, mh-local flags) ----------------
// 256 WGs x 512 threads, 1 WG/CU (LDS 160KB). bx = tile*4 + mh*2 + slot.
// slot0 phase p: layer0[t=p]; slot1 phase p: layer1[t=p-1]. h0,h1 x4 buffers.
// FLAG SEMANTICS: flag published at end of phase p is p+1; flag>=k <=> phase k-1 done.
// Flags grouped [slot][mh][64 tiles] — h rows never cross mh, so each gate polls
// only its same-mh 64-flag group (decongests the LLC flag lines 4x).
// Gates (wave0, single pollwait2 covering both groups):
//   slot0: slot0-grp >= p (h0[p-1] fresh), slot1-grp >= p-2 (h0[p-4] readers done)
//   slot1: slot0-grp >= p (h0[p-1] fresh), slot1-grp >= p   (h1[p-2] fresh)
// K-loop: ring-5 x 8KB per kw-window, prologue-4, steady vmcnt(12) (depth-4 covers
// the ~850cy coherent-LLC latency), WG s_barrier per round.
template <int SLOT>
__device__ void run_slot9(int mh, int tile,
                          const f16* __restrict__ xh,
                          const f16* __restrict__ wi, const f16* __restrict__ wh,
                          const float* __restrict__ bs,
                          f16* __restrict__ h0, f16* __restrict__ h1,
                          float* __restrict__ out, int* flags, char* lds)
{
    constexpr int K0 = SLOT ? 1024 : 512;   // x/h boundary of combined K
    constexpr int KW = SLOT ? 512 : 384;    // per-kw-window width (K/4)
    constexpr int NR = KW / 64;             // rounds per window (6 or 8)
    constexpr int NKS = KW / 16;
    const size_t BH = (size_t)B_ * H_;

    const int tid = threadIdx.x;
    const int wave = tid >> 6;
    const int lane = tid & 63;
    const int l31 = lane & 31, khi = lane >> 5;
    const int nw = wave & 1, kw = wave >> 1;
    const int n0 = tile * 16;
    const int rbase = mh * 64;

    // ---- W fragments -> registers (once, kc order) ----
    const int gcl = nw * 32 + l31;
    const size_t gr = (size_t)(gcl >> 4) * H_ + n0 + (gcl & 15);
    v8h wfrag[NKS];
#pragma unroll
    for (int s = 0; s < NKS; ++s) {
        const int k = kw * KW + s * 16 + khi * 8;
        const f16* p = (k < K0) ? (wi + gr * K0 + k) : (wh + gr * H_ + (k - K0));
        wfrag[s] = *(const v8h*)p;
    }

    // ---- per-thread cell state + biases (2 cells) ----
    const int urow = tid >> 3;
    const int un = (tid & 7) * 2;
    const float2 bI = *(const float2*)(bs + 0 * H_ + n0 + un);
    const float2 bF = *(const float2*)(bs + 1 * H_ + n0 + un);
    const float2 bG = *(const float2*)(bs + 2 * H_ + n0 + un);
    const float2 bO = *(const float2*)(bs + 3 * H_ + n0 + un);
    float c0r = 0.f, c1r = 0.f;

    int* f_pub = flags + (SLOT * 2 + mh) * 64;   // own publish group
    const int* fA = flags + mh * 64;             // slot0 same-mh group
    const int* fB = flags + (2 + mh) * 64;       // slot1 same-mh group

    float* gf = (float*)(lds + 49152);           // [64][68] f32 (post-join overlay)

    const int rw_ = lane >> 3;
    const int ss_ = (lane & 7) ^ rw_;            // pre-swizzled source 16B slot

#pragma unroll 1
    for (int p = 0; p <= T_; ++p) {
        const bool active = SLOT ? (p >= 1) : (p < T_);
        const int tau = SLOT ? p - 1 : p;

        const f16* srcA = nullptr; size_t strA = 0; const f16* srcB = nullptr; f16* hout = nullptr;
        if (active) {
            if (SLOT == 0) {
                srcA = xh + (size_t)tau * I_;  strA = (size_t)T_ * I_;   // x
                srcB = h0 + (size_t)((p + 3) & 3) * BH;                  // h0[p-1]
                hout = h0 + (size_t)(p & 3) * BH;                        // h0[p]
            } else {
                srcA = h0 + (size_t)((p + 3) & 3) * BH;  strA = H_;      // h0[p-1]
                srcB = h1 + (size_t)((p + 3) & 3) * BH;                  // h1[p-2]
                hout = h1 + (size_t)(p & 3) * BH;                        // h1[p-1]
            }
        }

        auto issue = [&](int r) {
            const int kc = kw * KW + r * 64;
            const f16* base; size_t str; int koff; bool coh;
            if (kc < K0) { base = srcA; str = strA; koff = kc; coh = (SLOT == 1); }
            else         { base = srcB; str = (size_t)H_; koff = kc - K0; coh = true; }
            char* dbase = lds + kw * 40960 + (r % 5) * 8192 + nw * 4096;
#pragma unroll
            for (int i = 0; i < 4; ++i) {
                const int rl = rbase + nw * 32 + i * 8 + rw_;
                const f16* gp = base + (size_t)rl * str + koff + ss_ * 8;
                if (coh) gl_lds16_coh(gp, dbase + i * 1024);
                else     gl_lds16(gp, dbase + i * 1024);
            }
        };

        v16f acc0 = {}, acc1 = {};

        auto compute = [&](int r) {
            const char* sb = lds + kw * 40960 + (r % 5) * 8192;
#pragma unroll
            for (int ks = 0; ks < 4; ++ks) {
                const int qo = (((ks * 2 + khi) ^ (l31 & 7)) << 4);
                const v8h a0 = *(const v8h*)(sb + l31 * 128 + qo);
                const v8h a1 = *(const v8h*)(sb + (32 + l31) * 128 + qo);
                __builtin_amdgcn_s_setprio(1);
                acc0 = __builtin_amdgcn_mfma_f32_32x32x16_f16(a0, wfrag[r * 4 + ks], acc0, 0, 0, 0);
                acc1 = __builtin_amdgcn_mfma_f32_32x32x16_f16(a1, wfrag[r * 4 + ks], acc1, 0, 0, 0);
                __builtin_amdgcn_s_setprio(0);
            }
        };

        if (active) {
            // ---- pre-gate prefetch of x-only rounds (slot0; x has no dependency) ----
            unsigned premask = 0;
            if (SLOT == 0) {
#pragma unroll
                for (int r = 0; r < 4; ++r)
                    if (kw * KW + r * 64 + 64 <= K0) { issue(r); premask |= 1u << r; }
            }

            // ---- gate: one dual-group poll by wave0 ----
            if (wave == 0) pollwait2(fA, p, fB, SLOT ? p : p - 2, lane);
            __syncthreads();
            __builtin_amdgcn_sched_barrier(0);

            // ---- remaining prologue (rounds 0..3) ----
#pragma unroll
            for (int r = 0; r < 4; ++r)
                if (!(premask & (1u << r))) issue(r);

            // ---- K-loop: depth-4, counted vmcnt, WG barrier per round ----
#pragma unroll
            for (int r = 0; r < NR; ++r) {
                if (r + 4 <= NR)      WAITV(12);
                else if (r + 3 == NR) WAITV(8);
                else if (r + 2 == NR) WAITV(4);
                else                  WAITV(0);
                BARX;
                if (r + 4 < NR) issue(r + 4);
                compute(r);
            }
            __syncthreads();   // join; rings idle -> overlay safe

            // ---- 2-stage reduction: 6 waves write partials; kw0 pair sums -> gf ----
            if (kw >= 1) {
                float* rg = (float*)lds + ((kw - 1) * 2 + nw) * 2048;
#pragma unroll
                for (int j = 0; j < 16; ++j) {
                    rg[j * 64 + lane] = acc0[j];
                    rg[(16 + j) * 64 + lane] = acc1[j];
                }
            }
            __syncthreads();
            if (kw == 0) {
                const float* r0 = (float*)lds + (0 + nw) * 2048;
                const float* r1 = (float*)lds + (2 + nw) * 2048;
                const float* r2 = (float*)lds + (4 + nw) * 2048;
#pragma unroll
                for (int j = 0; j < 16; ++j) {
                    const float s0 = acc0[j] + r0[j * 64 + lane] + r1[j * 64 + lane] + r2[j * 64 + lane];
                    const float s1 = acc1[j] + r0[(16 + j) * 64 + lane] + r1[(16 + j) * 64 + lane] + r2[(16 + j) * 64 + lane];
                    const int row = (j & 3) + 8 * (j >> 2) + 4 * khi;
                    gf[row * 68 + nw * 32 + l31] = s0;
                    gf[(32 + row) * 68 + nw * 32 + l31] = s1;
                }
            }
            __syncthreads();

            // ---- fused cell update: 2 cells/thread, c in registers ----
            {
                const float* g0 = gf + urow * 68 + un;
                const float xi0 = g0[0] + bI.x,  xi1 = g0[1] + bI.y;
                const float xf0 = g0[16] + bF.x, xf1 = g0[17] + bF.y;
                const float xg0 = g0[32] + bG.x, xg1 = g0[33] + bG.y;
                const float xo0 = g0[48] + bO.x, xo1 = g0[49] + bO.y;
                const float cn0 = fsigmoid(xf0) * c0r + fsigmoid(xi0) * ftanh(xg0);
                const float cn1 = fsigmoid(xf1) * c1r + fsigmoid(xi1) * ftanh(xg1);
                const float hn0 = fsigmoid(xo0) * ftanh(cn0);
                const float hn1 = fsigmoid(xo1) * ftanh(cn1);
                c0r = cn0; c1r = cn1;
                union { v2h h2; unsigned u; } cv;
                cv.h2[0] = (f16)hn0; cv.h2[1] = (f16)hn1;
                unsigned* hp = (unsigned*)(hout + (size_t)(rbase + urow) * H_ + n0 + un);
                asm volatile("global_store_dword %0, %1, off sc0 sc1" :: "v"(hp), "v"(cv.u) : "memory");
                if (SLOT == 1) {
                    float2 yv; yv.x = hn0; yv.y = hn1;
                    *(float2*)(out + ((size_t)(rbase + urow) * T_ + tau) * H_ + n0 + un) = yv;
                }
            }
        }

        // ---- arrive: drain stores, join, publish flag ----
        asm volatile("s_waitcnt vmcnt(0)" ::: "memory");
        __syncthreads();
        if (tid == 0) {
            int v = p + 1;
            int* fp = f_pub + tile;
            asm volatile("global_store_dword %0, %1, off sc0 sc1" :: "v"(fp), "v"(v) : "memory");
        }
    }
}

__global__ __launch_bounds__(512, 2) void lstm_persist9(
    const f16* __restrict__ xh,
    const f16* __restrict__ w0i, const f16* __restrict__ w0h,
    const f16* __restrict__ w1i, const f16* __restrict__ w1h,
    const float* __restrict__ bs0, const float* __restrict__ bs1,
    f16* __restrict__ h0, f16* __restrict__ h1, float* __restrict__ out,
    int* flags)
{
    __shared__ __align__(16) char lds[163840];   // 4 windows x ring-5 x 8KB
    const int bx = blockIdx.x;
    const int slot = bx & 1;
    const int mh = (bx >> 1) & 1;
    const int tile = bx >> 2;
    if (slot == 0)
        run_slot9<0>(mh, tile, xh, w0i, w0h, bs0, h0, h1, out, flags, lds);
    else
        run_slot9<1>(mh, tile, xh, w1i, w1h, bs1, h0, h1, out, flags, lds);
}

// ---------------- fp32 fallback (round-1 verified) ----------------
#define BM 64
#define NT 8

__global__ __launch_bounds__(256) void lstm_step(
    const float* __restrict__ A1, long a1_stride, int K1,
    const float* __restrict__ hprev,
    const float* __restrict__ Wih, const float* __restrict__ Whh,
    const float* __restrict__ bih, const float* __restrict__ bhh,
    float* __restrict__ cbuf, float* __restrict__ hout,
    float* yout, long y_stride)
{
    __shared__ float As[32][66];
    __shared__ float Ws[32][36];
    const int tid = threadIdx.x;
    const int n0 = blockIdx.x * NT;
    const int b0 = blockIdx.y * BM;
    const int tb = tid >> 3;
    const int tc = tid & 7;
    const int lr = tid >> 3;
    const int lk = tid & 7;
    const long wj = (long)(lr >> 3) * H_ + n0 + (lr & 7);
    float acc[2][4] = {{0.f, 0.f, 0.f, 0.f}, {0.f, 0.f, 0.f, 0.f}};
#pragma unroll 1
    for (int ph = 0; ph < 2; ++ph) {
        const float* Ap = (ph == 0) ? A1 : hprev;
        const long as = (ph == 0) ? a1_stride : (long)H_;
        const float* W = (ph == 0) ? Wih : Whh;
        const int K = (ph == 0) ? K1 : H_;
        const float* arow0 = Ap + (long)(b0 + lr) * as + 4 * lk;
        const float* arow1 = Ap + (long)(b0 + lr + 32) * as + 4 * lk;
        const float* wrow = W + wj * K + 4 * lk;
        float4 ra0 = *(const float4*)(arow0);
        float4 ra1 = *(const float4*)(arow1);
        float4 rw = *(const float4*)(wrow);
        for (int k0 = 0; k0 < K; k0 += 32) {
            __syncthreads();
            {
                const int kk = 4 * lk;
                As[kk + 0][lr] = ra0.x; As[kk + 1][lr] = ra0.y;
                As[kk + 2][lr] = ra0.z; As[kk + 3][lr] = ra0.w;
                As[kk + 0][lr + 32] = ra1.x; As[kk + 1][lr + 32] = ra1.y;
                As[kk + 2][lr + 32] = ra1.z; As[kk + 3][lr + 32] = ra1.w;
                Ws[kk + 0][lr] = rw.x; Ws[kk + 1][lr] = rw.y;
                Ws[kk + 2][lr] = rw.z; Ws[kk + 3][lr] = rw.w;
            }
            __syncthreads();
            const int kn = k0 + 32;
            if (kn < K) {
                ra0 = *(const float4*)(arow0 + kn);
                ra1 = *(const float4*)(arow1 + kn);
                rw = *(const float4*)(wrow + kn);
            }
#pragma unroll
            for (int k = 0; k < 32; ++k) {
                float2 a = *(const float2*)&As[k][2 * tb];
                float4 w = *(const float4*)&Ws[k][4 * tc];
                acc[0][0] = fmaf(a.x, w.x, acc[0][0]);
                acc[0][1] = fmaf(a.x, w.y, acc[0][1]);
                acc[0][2] = fmaf(a.x, w.z, acc[0][2]);
                acc[0][3] = fmaf(a.x, w.w, acc[0][3]);
                acc[1][0] = fmaf(a.y, w.x, acc[1][0]);
                acc[1][1] = fmaf(a.y, w.y, acc[1][1]);
                acc[1][2] = fmaf(a.y, w.z, acc[1][2]);
                acc[1][3] = fmaf(a.y, w.w, acc[1][3]);
            }
        }
    }
    __syncthreads();
    float* gsf = &As[0][0];
#pragma unroll
    for (int bi = 0; bi < 2; ++bi)
#pragma unroll
        for (int ci = 0; ci < 4; ++ci)
            gsf[(2 * tb + bi) * 33 + 4 * tc + ci] = acc[bi][ci];
    __syncthreads();
    const int dn = tid & 7;
    const int bq = tid >> 3;
    const int n = n0 + dn;
#pragma unroll
    for (int s = 0; s < 2; ++s) {
        const int b = bq + 32 * s;
        float xi = gsf[b * 33 + dn] + bih[n] + bhh[n];
        float xf = gsf[b * 33 + 8 + dn] + bih[H_ + n] + bhh[H_ + n];
        float xg = gsf[b * 33 + 16 + dn] + bih[2 * H_ + n] + bhh[2 * H_ + n];
        float xo = gsf[b * 33 + 24 + dn] + bih[3 * H_ + n] + bhh[3 * H_ + n];
        const long idx = (long)(b0 + b) * H_ + n;
        const float c_old = cbuf[idx];
        const float cn = fsigmoid(xf) * c_old + fsigmoid(xi) * ftanh(xg);
        const float hn = fsigmoid(xo) * ftanh(cn);
        cbuf[idx] = cn;
        hout[idx] = hn;
        if (yout) yout[(long)(b0 + b) * y_stride + n] = hn;
    }
}

extern "C" void kernel_launch(void* const* d_in, const int* in_sizes, int n_in,
                              void* d_out, int out_size, void* d_ws, size_t ws_size,
                              hipStream_t stream) {
    const float* x = (const float*)d_in[0];
    const float* Wih0 = (const float*)d_in[1];
    const float* Whh0 = (const float*)d_in[2];
    const float* bih0 = (const float*)d_in[3];
    const float* bhh0 = (const float*)d_in[4];
    const float* Wih1 = (const float*)d_in[5];
    const float* Whh1 = (const float*)d_in[6];
    const float* bih1 = (const float*)d_in[7];
    const float* bhh1 = (const float*)d_in[8];
    float* out = (float*)d_out;

    const size_t BH = (size_t)B_ * H_;
    const size_t NX = (size_t)B_ * T_ * I_;
    const size_t NW0I = (size_t)4 * H_ * I_;
    const size_t NWH = (size_t)4 * H_ * H_;

    const size_t off_xh = 0;
    const size_t off_w0i = off_xh + NX * 2;
    const size_t off_w0h = off_w0i + NW0I * 2;
    const size_t off_w1i = off_w0h + NWH * 2;
    const size_t off_w1h = off_w1i + NWH * 2;
    const size_t off_bs0 = off_w1h + NWH * 2;
    const size_t off_bs1 = off_bs0 + 4 * H_ * 4;
    const size_t off_h0 = off_bs1 + 4 * H_ * 4;        // 4 buffers
    const size_t off_h1 = off_h0 + 4 * BH * 2;         // 4 buffers
    const size_t off_flags = off_h1 + 4 * BH * 2;      // [slot][mh][64] packed ints
    const size_t REQ = off_flags + 256 * 4;

    char* ws = (char*)d_ws;

    if (ws_size >= REQ) {
        f16* xh = (f16*)(ws + off_xh);
        f16* w0i = (f16*)(ws + off_w0i);
        f16* w0h = (f16*)(ws + off_w0h);
        f16* w1i = (f16*)(ws + off_w1i);
        f16* w1h = (f16*)(ws + off_w1h);
        float* bs0 = (float*)(ws + off_bs0);
        float* bs1 = (float*)(ws + off_bs1);
        f16* h0 = (f16*)(ws + off_h0);
        f16* h1 = (f16*)(ws + off_h1);
        int* flags = (int*)(ws + off_flags);

        // zero h0, h1, flags — contiguous tail
        hipMemsetAsync(ws + off_h0, 0, REQ - off_h0, stream);

        dim3 cb(256);
        k_f32_to_f16<<<2048, cb, 0, stream>>>(x, xh, (int)NX);
        k_f32_to_f16<<<2048, cb, 0, stream>>>(Wih0, w0i, (int)NW0I);
        k_f32_to_f16<<<2048, cb, 0, stream>>>(Whh0, w0h, (int)NWH);
        k_f32_to_f16<<<2048, cb, 0, stream>>>(Wih1, w1i, (int)NWH);
        k_f32_to_f16<<<2048, cb, 0, stream>>>(Whh1, w1h, (int)NWH);
        k_bias_sum<<<16, cb, 0, stream>>>(bih0, bhh0, bs0, 4 * H_);
        k_bias_sum<<<16, cb, 0, stream>>>(bih1, bhh1, bs1, 4 * H_);

        lstm_persist9<<<256, 512, 0, stream>>>(xh, w0i, w0h, w1i, w1h, bs0, bs1,
                                               h0, h1, out, flags);
        return;
    }

    // ---------- fp32 fallback ----------
    float* fws = (float*)d_ws;
    float* h0a = fws;
    float* h0b = fws + BH;
    float* c0 = fws + 2 * BH;
    float* h1a = fws + 3 * BH;
    float* h1b = fws + 4 * BH;
    float* c1 = fws + 5 * BH;
    hipMemsetAsync(d_ws, 0, 6 * BH * sizeof(float), stream);

    dim3 grid(H_ / NT, B_ / BM);
    dim3 block(256);
    for (int t = 0; t < T_; ++t) {
        float* h0in = (t & 1) ? h0b : h0a;
        float* h0out = (t & 1) ? h0a : h0b;
        float* h1in = (t & 1) ? h1b : h1a;
        float* h1out = (t & 1) ? h1a : h1b;
        lstm_step<<<grid, block, 0, stream>>>(
            x + (size_t)t * I_, (long)T_ * I_, I_,
            h0in, Wih0, Whh0, bih0, bhh0, c0, h0out, nullptr, 0);
        lstm_step<<<grid, block, 0, stream>>>(
            h0out, (long)H_, H_,
            h1in, Wih1, Whh1, bih1, bhh1, c1, h1out,
            out + (size_t)t * H_, (long)T_ * H_);
    }
}